// Round 9
// baseline (111.979 us; speedup 1.0000x reference)
//
#include <hip/hip_runtime.h>
#include <stdint.h>

typedef unsigned short u16;
typedef __attribute__((ext_vector_type(4))) u16    u16x4;
typedef __attribute__((ext_vector_type(8))) u16    u16x8;
typedef __attribute__((ext_vector_type(4))) float  f32x4;
typedef __attribute__((ext_vector_type(8))) __bf16 bf16x8;

union BF8 { u16x8 u; bf16x8 b; };

__device__ __forceinline__ u16 f2bf(float f) {
    union { float f; uint32_t u; } v; v.f = f;
    uint32_t u = v.u;
    uint32_t rb = 0x7FFFu + ((u >> 16) & 1u);
    return (u16)((u + rb) >> 16);
}

__device__ __forceinline__ bf16x8 cvt8(f32x4 a, f32x4 b) {
    bf16x8 r;
    r[0] = (__bf16)a.x; r[1] = (__bf16)a.y; r[2] = (__bf16)a.z; r[3] = (__bf16)a.w;
    r[4] = (__bf16)b.x; r[5] = (__bf16)b.y; r[6] = (__bf16)b.z; r[7] = (__bf16)b.w;
    return r;
}

// ---------------- prep: xT[b][g][n] bf16  +  WaTp (pi-permuted W-aug) ------
// Wa[g][f]: g<128 -> W[g][f]; g==128 -> bias[f]; g>128 -> 0.
// WaTp[f][c*32 + lg*8 + jj] = Wa[c*32 + pi(lg,jj)][f],
//   pi(lg,jj) = jj<4 ? lg*4+jj : 16 + lg*4 + (jj-4)   (R6-HW-verified map)
__global__ __launch_bounds__(256) void gcn_prep(const float* __restrict__ x,
                                                const float* __restrict__ W,
                                                const float* __restrict__ bias,
                                                u16* __restrict__ xT,
                                                u16* __restrict__ WaTp) {
    const int t = threadIdx.x;
    if (blockIdx.x == 512) {     // WaTp: 128 f x 160 slots
#pragma unroll
        for (int i = 0; i < 80; ++i) {
            int idx = i * 256 + t;                 // 0..20479
            int f = idx / 160, pp = idx % 160;
            int c = pp >> 5, lg = (pp >> 3) & 3, jj = pp & 7;
            int g = c * 32 + (jj < 4 ? lg * 4 + jj : 16 + lg * 4 + (jj - 4));
            float v = (g < 128) ? W[(size_t)g * 128 + f]
                                : (g == 128 ? bias[f] : 0.0f);
            WaTp[f * 160 + pp] = f2bf(v);
        }
        return;
    }
    __shared__ u16 Xt[64 * 128];                   // [n][g] bf16 tile
    const int bb = blockIdx.x >> 4;
    const int n0 = (blockIdx.x & 15) << 6;
    const float* xb = x + (size_t)bb * 131072 + (size_t)n0 * 128;
#pragma unroll
    for (int i = 0; i < 8; ++i) {
        int o4 = i * 256 + t;                      // 2048 f32x4 chunks
        f32x4 v = *(const f32x4*)(xb + (size_t)o4 * 4);
        u16x4 hv; hv.x = f2bf(v.x); hv.y = f2bf(v.y);
        hv.z = f2bf(v.z); hv.w = f2bf(v.w);
        *(u16x4*)(Xt + o4 * 4) = hv;
    }
    __syncthreads();
    const int g = t >> 1, nh = (t & 1) * 32;
    u16* dst = xT + (size_t)bb * 131072 + (size_t)g * 1024 + n0 + nh;
#pragma unroll
    for (int q = 0; q < 4; ++q) {
        u16x8 v;
#pragma unroll
        for (int j = 0; j < 8; ++j) v[j] = Xt[(nh + q * 8 + j) * 128 + g];
        *(u16x8*)(dst + q * 8) = v;
    }
}

// ---------------- main: out = relu((adj@x)@Wa + x) -------------------------
// Block: 64 adj rows. 8 waves = 4 r-tiles x 2 n-halves. NO LDS/barriers in
// the adj-stream loop; one syncthreads to combine n-half partials.
__global__ __launch_bounds__(512, 4)
void gcn_main(const float* __restrict__ adj, const float* __restrict__ x,
              const u16* __restrict__ xT, const u16* __restrict__ WaTp,
              float* __restrict__ out) {
    __shared__ f32x4 Plds[8 * 9 * 64];   // 72 KB partial y2T

    const int t = threadIdx.x;
    // bijective XCD swizzle: one XCD owns 4 whole batches
    const int L   = (blockIdx.x & 7) * 64 + (blockIdx.x >> 3);
    const int bb  = L >> 4;
    const int r0b = (L & 15) << 6;
    const int w = t >> 6, l = t & 63;
    const int lc = l & 15, lg = l >> 4;
    const int p = w >> 1, h = w & 1;      // r-tile, n-half
    const int r0w = r0b + p * 16;

    const float* adjRow = adj + (size_t)bb * 1048576 + (size_t)(r0w + lc) * 1024 + lg * 8;
    const u16*   xTrow  = xT + (size_t)bb * 131072 + (size_t)lc * 1024 + lg * 8;

    BF8 ones;                              // xT row 128 == 1.0 (rowsum trick)
    {
        u16 o = (lc == 0) ? (u16)0x3F80 : (u16)0;
#pragma unroll
        for (int j = 0; j < 8; ++j) ones.u[j] = o;
    }

    f32x4 y2[9] = {};                      // y2T D-tiles gt=0..8
    const int ntBase = h * 512;            // n-element offset of this half

    f32x4 a0 = *(const f32x4*)(adjRow + ntBase);
    f32x4 a1 = *(const f32x4*)(adjRow + ntBase + 4);
    u16x8 xc[8];
#pragma unroll
    for (int gt = 0; gt < 8; ++gt)
        xc[gt] = *(const u16x8*)(xTrow + gt * 16384 + ntBase);

#pragma unroll
    for (int i = 0; i < 16; ++i) {
        const int nOff = ntBase + i * 32;
        f32x4 na0, na1; u16x8 nx[8];
        if (i < 15) {
            na0 = *(const f32x4*)(adjRow + nOff + 32);
            na1 = *(const f32x4*)(adjRow + nOff + 36);
#pragma unroll
            for (int gt = 0; gt < 8; ++gt)
                nx[gt] = *(const u16x8*)(xTrow + gt * 16384 + nOff + 32);
        }
        BF8 bf; bf.b = cvt8(a0, a1);       // adj B-frag (k = n slots)
#pragma unroll
        for (int gt = 0; gt < 8; ++gt) {
            BF8 xa; xa.u = xc[gt];
            y2[gt] = __builtin_amdgcn_mfma_f32_16x16x32_bf16(xa.b, bf.b, y2[gt], 0, 0, 0);
        }
        y2[8] = __builtin_amdgcn_mfma_f32_16x16x32_bf16(ones.b, bf.b, y2[8], 0, 0, 0);
        if (i < 15) {
            a0 = na0; a1 = na1;
#pragma unroll
            for (int gt = 0; gt < 8; ++gt) xc[gt] = nx[gt];
        }
    }

    // combine the two n-halves of each r-tile through LDS (one barrier total)
#pragma unroll
    for (int gt = 0; gt < 9; ++gt)
        Plds[(w * 9 + gt) * 64 + l] = y2[gt];
    __syncthreads();

    f32x4 ys[9];
#pragma unroll
    for (int gt = 0; gt < 9; ++gt)
        ys[gt] = Plds[((p * 2) * 9 + gt) * 64 + l] +
                 Plds[((p * 2 + 1) * 9 + gt) * 64 + l];

    // second gemm: z[f][r] = sum_g Wa[g][f] * y2[r][g], K=160 (5 chunks)
    f32x4 z[4] = {};
#pragma unroll
    for (int c = 0; c < 5; ++c) {
        BF8 breg;
#pragma unroll
        for (int jj = 0; jj < 4; ++jj) breg.b[jj] = (__bf16)ys[2 * c][jj];
#pragma unroll
        for (int jj = 0; jj < 4; ++jj)
            breg.b[4 + jj] = (c < 4) ? (__bf16)ys[2 * c + 1][jj] : (__bf16)0.0f;
#pragma unroll
        for (int ft = 0; ft < 4; ++ft) {
            int f = h * 64 + ft * 16 + lc;
            BF8 aw;
            aw.u = *(const u16x8*)(WaTp + f * 160 + c * 32 + lg * 8);
            z[ft] = __builtin_amdgcn_mfma_f32_16x16x32_bf16(aw.b, breg.b, z[ft], 0, 0, 0);
        }
    }

    // epilogue: + x, relu, fp32 store.  z-D: row=f (lg*4+j), col=r (lc)
    const int r = r0w + lc;
    const float* xres = x + (size_t)bb * 131072 + (size_t)r * 128;
    float*       ob   = out + (size_t)bb * 131072 + (size_t)r * 128;
#pragma unroll
    for (int ft = 0; ft < 4; ++ft) {
        int fb = h * 64 + ft * 16 + lg * 4;
        f32x4 xv = *(const f32x4*)(xres + fb);
        f32x4 v;
#pragma unroll
        for (int j = 0; j < 4; ++j) v[j] = fmaxf(z[ft][j] + xv[j], 0.0f);
        *(f32x4*)(ob + fb) = v;
    }
}

extern "C" void kernel_launch(void* const* d_in, const int* in_sizes, int n_in,
                              void* d_out, int out_size, void* d_ws, size_t ws_size,
                              hipStream_t stream) {
    const float* x    = (const float*)d_in[0];
    const float* adj  = (const float*)d_in[1];
    const float* W    = (const float*)d_in[2];
    const float* bias = (const float*)d_in[3];
    float* out = (float*)d_out;

    u16* xT   = (u16*)d_ws;                                  // 8 MiB
    u16* WaTp = (u16*)((char*)d_ws + (size_t)8 * 1024 * 1024); // +40 KiB

    gcn_prep<<<dim3(513), dim3(256), 0, stream>>>(x, W, bias, xT, WaTp);
    gcn_main<<<dim3(512), dim3(512), 0, stream>>>(adj, x, xT, WaTp, out);
}

// Round 10
// 42.435 us; speedup vs baseline: 2.6388x; 2.6388x over previous
//
#include <hip/hip_runtime.h>
#include <stdint.h>

typedef unsigned short u16;
typedef __attribute__((ext_vector_type(4))) u16    u16x4;
typedef __attribute__((ext_vector_type(8))) u16    u16x8;
typedef __attribute__((ext_vector_type(4))) float  f32x4;
typedef __attribute__((ext_vector_type(4))) __bf16 bf16x4;
typedef __attribute__((ext_vector_type(8))) __bf16 bf16x8;

union BF8 { u16x8 u; bf16x8 b; };
union BF4 { u16x4 u; bf16x4 b; };

// native casts -> v_cvt_pk_bf16_f32 (compiler-emitted, m240)
__device__ __forceinline__ u16x4 cvt4(f32x4 a) {
    BF4 r;
    r.b[0] = (__bf16)a.x; r.b[1] = (__bf16)a.y;
    r.b[2] = (__bf16)a.z; r.b[3] = (__bf16)a.w;
    return r.u;
}
__device__ __forceinline__ u16x8 cvt8u(f32x4 a, f32x4 b) {
    BF8 r;
    r.b[0] = (__bf16)a.x; r.b[1] = (__bf16)a.y; r.b[2] = (__bf16)a.z; r.b[3] = (__bf16)a.w;
    r.b[4] = (__bf16)b.x; r.b[5] = (__bf16)b.y; r.b[6] = (__bf16)b.z; r.b[7] = (__bf16)b.w;
    return r.u;
}
__device__ __forceinline__ u16 cvt1(float f) {
    union { __bf16 b; u16 u; } c; c.b = (__bf16)f; return c.u;
}

// ---------------- kernel 0: W[k][f] -> Wt[f][k] bf16 ----------------
__global__ __launch_bounds__(256) void gcn_wt(const float* __restrict__ W,
                                              u16* __restrict__ Wt) {
    int idx = blockIdx.x * 256 + threadIdx.x;   // 0..16383
    int k = idx >> 7, f = idx & 127;
    Wt[f * 128 + k] = cvt1(W[idx]);
}

// ---------------- kernel 1: hT[b][f][n] = bf16((x@W)^T + b) ----------------
__global__ __launch_bounds__(256) void gcn_xw(const float* __restrict__ x,
                                              const u16* __restrict__ Wt,
                                              const float* __restrict__ bias,
                                              u16* __restrict__ hT) {
    __shared__ u16 Wl[128 * 128];   // [f][k] swizzled (256B rows)
    __shared__ u16 Xl[128 * 128];   // [n][k] swizzled (256B rows)
    const int t  = threadIdx.x;
    const int bb = blockIdx.x >> 3;
    const int n0 = (blockIdx.x & 7) << 7;

#pragma unroll
    for (int i = 0; i < 16; ++i) {
        int o  = i * 256 + t;          // 8B chunk index, 0..4095
        int f  = o >> 5;
        int kb = (o & 31) * 8;
        u16x4 v = *(const u16x4*)((const char*)Wt + o * 8);
        *(u16x4*)((char*)Wl + f * 256 + (kb ^ ((f & 7) << 4))) = v;
    }
    const float* xb = x + (size_t)bb * (1024 * 128) + (size_t)n0 * 128;
#pragma unroll
    for (int i = 0; i < 16; ++i) {
        int o4 = i * 256 + t;
        int n  = o4 >> 5;
        int kb = (o4 & 31) * 8;
        f32x4 v = *(const f32x4*)(xb + (size_t)o4 * 4);
        *(u16x4*)((char*)Xl + n * 256 + (kb ^ ((n & 7) << 4))) = cvt4(v);
    }
    __syncthreads();

    const int w = t >> 6, l = t & 63;
    const int wr = w >> 1, wc = w & 1;
    f32x4 acc[4][4] = {};
#pragma unroll
    for (int kk = 0; kk < 4; ++kk) {
        const int kbyte = kk * 64 + (l >> 4) * 16;
        bf16x8 a[4], b[4];
#pragma unroll
        for (int mf = 0; mf < 4; ++mf) {
            int fl = wr * 64 + mf * 16 + (l & 15);
            a[mf] = *(const bf16x8*)((const char*)Wl + fl * 256 + (kbyte ^ ((fl & 7) << 4)));
        }
#pragma unroll
        for (int nn = 0; nn < 4; ++nn) {
            int nl = wc * 64 + nn * 16 + (l & 15);
            b[nn] = *(const bf16x8*)((const char*)Xl + nl * 256 + (kbyte ^ ((nl & 7) << 4)));
        }
#pragma unroll
        for (int mf = 0; mf < 4; ++mf)
#pragma unroll
            for (int nn = 0; nn < 4; ++nn)
                acc[mf][nn] = __builtin_amdgcn_mfma_f32_16x16x32_bf16(
                    a[mf], b[nn], acc[mf][nn], 0, 0, 0);
    }

    u16* ho = hT + (size_t)bb * 131072;
#pragma unroll
    for (int mf = 0; mf < 4; ++mf) {
        int fbase = wr * 64 + mf * 16 + (l >> 4) * 4;
#pragma unroll
        for (int r = 0; r < 4; ++r) {
            float bv = bias[fbase + r];
#pragma unroll
            for (int nn = 0; nn < 4; ++nn) {
                int n = wc * 64 + nn * 16 + (l & 15);
                ho[(size_t)(fbase + r) * 1024 + n0 + n] = cvt1(acc[mf][nn][r] + bv);
            }
        }
    }
}

// ---------------- kernel 2: out = relu(adj @ h + x) ----------------
// R4-proven: BM=64, BN=128, BK=64; 512 thr (8 waves, wave 16r x 64f);
// reg depth-2 prefetch; LDS dbuf; raw lgkm-barrier (vmcnt stays in flight).
// ONLY change vs R4: staging cvt via v_cvt_pk (native casts).
__global__ __launch_bounds__(512, 4) void gcn_agg(const float* __restrict__ adj,
                                                  const u16* __restrict__ hT,
                                                  const float* __restrict__ x,
                                                  float* __restrict__ out) {
    __shared__ u16 Al[2][64 * 64];      // bf16 adj tile, 8 KB each, swizzled
    __shared__ u16 Bl[2][128 * 64];     // bf16 hT tile, 16 KB each, swizzled

    const int t = threadIdx.x;          // 0..511
    const int L  = (blockIdx.x & 7) * 64 + (blockIdx.x >> 3);
    const int bb = L >> 4;
    const int r0 = (L & 15) << 6;

    const float* adjb = adj + (size_t)bb * 1048576 + (size_t)r0 * 1024;
    const u16*   hTb  = hT + (size_t)bb * 131072;

    const int w = t >> 6, l = t & 63;
    const int wr = w >> 1, wc = w & 1;  // 4x2 wave grid: 16 rows x 64 f each

    const int rA = t >> 3, k8 = t & 7;
    const float* gA  = adjb + (size_t)rA * 1024 + k8 * 8;
    const u16*   gB0 = hTb + (size_t)rA * 1024 + k8 * 8;
    const u16*   gB1 = gB0 + 64 * 1024;
    const int ldsA  = rA * 128 + ((k8 * 16) ^ ((rA & 7) << 4));
    const int ldsB0 = ldsA;
    const int ldsB1 = (64 + rA) * 128 + ((k8 * 16) ^ ((rA & 7) << 4));

#define LOADT(ar, br, ks)                                   \
    do {                                                    \
        const int k0 = (ks) * 64;                           \
        ar[0] = *(const f32x4*)(gA + k0);                   \
        ar[1] = *(const f32x4*)(gA + k0 + 4);               \
        br[0] = *(const u16x8*)(gB0 + k0);                  \
        br[1] = *(const u16x8*)(gB1 + k0);                  \
    } while (0)

#define WRITET(buf, ar, br)                                 \
    do {                                                    \
        *(u16x8*)((char*)&Al[buf][0] + ldsA)  = cvt8u(ar[0], ar[1]); \
        *(u16x8*)((char*)&Bl[buf][0] + ldsB0) = br[0];      \
        *(u16x8*)((char*)&Bl[buf][0] + ldsB1) = br[1];      \
    } while (0)

#define BARRIER() asm volatile("s_waitcnt lgkmcnt(0)\ns_barrier" ::: "memory")

#define COMPUTE(buf)                                                            \
    do {                                                                        \
        _Pragma("unroll")                                                       \
        for (int kk = 0; kk < 2; ++kk) {                                        \
            const int kbyte = kk * 64 + (l >> 4) * 16;                          \
            const int rl = wr * 16 + (l & 15);                                  \
            bf16x8 a = *(const bf16x8*)((const char*)&Al[buf][0] + rl * 128 +   \
                                        (kbyte ^ ((rl & 7) << 4)));             \
            bf16x8 b[4];                                                        \
            _Pragma("unroll")                                                   \
            for (int nn = 0; nn < 4; ++nn) {                                    \
                int fl = wc * 64 + nn * 16 + (l & 15);                          \
                b[nn] = *(const bf16x8*)((const char*)&Bl[buf][0] + fl * 128 +  \
                                         (kbyte ^ ((fl & 7) << 4)));            \
            }                                                                   \
            _Pragma("unroll")                                                   \
            for (int nn = 0; nn < 4; ++nn)                                      \
                acc[nn] = __builtin_amdgcn_mfma_f32_16x16x32_bf16(              \
                    a, b[nn], acc[nn], 0, 0, 0);                                \
        }                                                                       \
    } while (0)

    f32x4 acc[4] = {};
    f32x4 a0[2], a1[2];
    u16x8 b0[2], b1[2];

    LOADT(a0, b0, 0);
    LOADT(a1, b1, 1);
#pragma unroll
    for (int ks = 0; ks < 16; ks += 2) {
        WRITET(0, a0, b0);
        BARRIER();
        if (ks + 2 < 16) LOADT(a0, b0, ks + 2);
        COMPUTE(0);
        WRITET(1, a1, b1);
        BARRIER();
        if (ks + 3 < 16) LOADT(a1, b1, ks + 3);
        COMPUTE(1);
    }
#undef LOADT
#undef WRITET
#undef BARRIER
#undef COMPUTE

    // epilogue: + x, relu, fp32 store
    const float* xb = x + (size_t)bb * 131072;
    float*       ob = out + (size_t)bb * 131072;
#pragma unroll
    for (int j = 0; j < 4; ++j) {
        int r = r0 + wr * 16 + (l >> 4) * 4 + j;
#pragma unroll
        for (int nn = 0; nn < 4; ++nn) {
            int f = wc * 64 + nn * 16 + (l & 15);
            size_t idx = (size_t)r * 128 + f;
            float v = acc[nn][j] + xb[idx];
            ob[idx] = fmaxf(v, 0.0f);
        }
    }
}

extern "C" void kernel_launch(void* const* d_in, const int* in_sizes, int n_in,
                              void* d_out, int out_size, void* d_ws, size_t ws_size,
                              hipStream_t stream) {
    const float* x    = (const float*)d_in[0];
    const float* adj  = (const float*)d_in[1];
    const float* W    = (const float*)d_in[2];
    const float* bias = (const float*)d_in[3];
    float* out = (float*)d_out;

    u16* hT = (u16*)d_ws;                                    // 8 MiB
    u16* Wt = (u16*)((char*)d_ws + (size_t)32 * 131072 * 2); // +32 KiB

    gcn_wt <<<dim3(64),  dim3(256), 0, stream>>>(W, Wt);
    gcn_xw <<<dim3(256), dim3(256), 0, stream>>>(x, Wt, bias, hT);
    gcn_agg<<<dim3(512), dim3(512), 0, stream>>>(adj, hT, x, out);
}